// Round 9
// baseline (445.071 us; speedup 1.0000x reference)
//
#include <hip/hip_runtime.h>

#define DEV __device__ __forceinline__

typedef __attribute__((ext_vector_type(8))) short bfx8;
typedef __attribute__((ext_vector_type(4))) float fx4;

typedef __attribute__((address_space(3))) unsigned int as3_u32;
typedef const __attribute__((address_space(1))) unsigned int as1_u32c;

DEV void gl_lds16(const void* g, const void* l) {
  __builtin_amdgcn_global_load_lds((as1_u32c*)(unsigned long long)g,
                                   (as3_u32*)(unsigned long long)l, 16, 0, 0);
}

DEV short f2bf(float f) {
  unsigned u = __float_as_uint(f);
  u += 0x7fffu + ((u >> 16) & 1u);
  return (short)(u >> 16);
}
DEV float bf2f(short s) {
  return __uint_as_float(((unsigned)(unsigned short)s) << 16);
}
DEV float gelu_f(float x) { return 0.5f * x * (1.0f + erff(x * 0.70710678118654752f)); }

#define MFMA16(acc, a, b) (acc) = __builtin_amdgcn_mfma_f32_16x16x32_bf16((a), (b), (acc), 0, 0, 0)

// ---------------- conversions ----------------
struct CvtSeg { const float* src; short* dst; int n; };
struct CvtArgs { CvtSeg s[7]; };

__global__ __launch_bounds__(256) void cvt_multi(CvtArgs a) {
  CvtSeg s = a.s[blockIdx.y];
  int i = ((int)blockIdx.x * 256 + (int)threadIdx.x) * 8;
  if (i >= s.n) return;
  bfx8 o;
  #pragma unroll
  for (int j = 0; j < 8; ++j) o[j] = f2bf(s.src[i + j]);
  *(bfx8*)(s.dst + i) = o;
}

// conv2_w (768,256,3,3) -> W2t [tap][o][c]
__global__ __launch_bounds__(256) void cvt_conv2w(const float* src, short* dst) {
  int oc = (int)blockIdx.x * 256 + (int)threadIdx.x;
  const float* s = src + (long)oc * 9;
  float t[9];
  #pragma unroll
  for (int j = 0; j < 9; ++j) t[j] = s[j];
  #pragma unroll
  for (int tap = 0; tap < 9; ++tap)
    dst[(long)tap * (768 * 256) + oc] = f2bf(t[tap]);
}

// ebc[n] = e1b[n] + sum_c ob[c]*e1w[n][c]
__global__ __launch_bounds__(64) void ebc2(const float* e1w, const float* e1b, const float* ob, float* ebc) {
  int n = blockIdx.x, lane = threadIdx.x;
  float s = 0.0f;
  #pragma unroll
  for (int i = 0; i < 4; ++i) {
    int c = lane + 64 * i;
    s += ob[c] * e1w[(long)n * 512 + c];
  }
  #pragma unroll
  for (int off = 1; off < 64; off <<= 1) s += __shfl_xor(s, off);
  if (lane == 0) ebc[n] = e1b[n] + s;
}

// fused: Wcomb[m][d] = sum_c E1a[m][c] * ow[c][d]  (in-kernel transpose of ow)
__global__ __launch_bounds__(256) void wcombk(const float* ow, const short* Wep1, short* Wcomb) {
  __shared__ short Bt[64 * 264];
  const int t = threadIdx.x;
  const int lane = t & 63, w = t >> 6;
  const int lg = lane >> 4, li = lane & 15;
  const int m0 = blockIdx.y * 64, n0 = blockIdx.x * 64;
  for (int idx = t; idx < 64 * 256; idx += 256) {
    int c = idx >> 6, d = idx & 63;
    Bt[d * 264 + c] = f2bf(ow[(long)c * 256 + n0 + d]);
  }
  __syncthreads();
  fx4 acc[4] = {};
  const short* aR = Wep1 + (long)(m0 + w * 16 + li) * 512 + lg * 8;
  for (int kc = 0; kc < 256; kc += 32) {
    bfx8 a = *(const bfx8*)(aR + kc);
    #pragma unroll
    for (int ni = 0; ni < 4; ++ni) {
      bfx8 bv = *(const bfx8*)(&Bt[(ni * 16 + li) * 264 + kc + lg * 8]);
      MFMA16(acc[ni], a, bv);
    }
  }
  #pragma unroll
  for (int ni = 0; ni < 4; ++ni)
    #pragma unroll
    for (int r = 0; r < 4; ++r)
      Wcomb[(long)(m0 + w * 16 + 4 * lg + r) * 256 + n0 + ni * 16 + li] = f2bf(acc[ni][r]);
}

// ---------------- fused transpose + conv1(1x1) + gelu (+ zero borders of xP) ----------------
DEV int axc(int p, int c) { return p * 260 + (c ^ (((p >> 2) & 7) << 2)); }

__global__ __launch_bounds__(256) void tc1(const float* fm, const short* W1bf,
                                           const float* b1, short* xP) {
  __shared__ float Af[64 * 260];
  const int lane = threadIdx.x & 63, wv = threadIdx.x >> 6;
  const int lg = lane >> 4, li = lane & 15;
  const int y = blockIdx.x & 63, b = blockIdx.x >> 6;
  const int t = threadIdx.x;
  short* dstP = xP + ((long)b * 66 * 66 + (long)(y + 1) * 66 + 1) * 256;
  const bfx8 z8 = {0, 0, 0, 0, 0, 0, 0, 0};

  // zero padded borders (replaces memset of xP)
  if (t < 64) {
    if (t < 32) *(bfx8*)(dstP - 256 + t * 8) = z8;          // left col x=0
    else        *(bfx8*)(dstP + 64 * 256 + (t - 32) * 8) = z8;  // right col x=65
  }
  if (y == 0) {
    short* top = xP + (long)b * 66 * 66 * 256;
    for (int i = t; i < 2112; i += 256) *(bfx8*)(top + i * 8) = z8;
  }
  if (y == 63) {
    short* bot = xP + ((long)b * 66 * 66 + 65 * 66) * 256;
    for (int i = t; i < 2112; i += 256) *(bfx8*)(bot + i * 8) = z8;
  }

  const float* src = fm + (long)b * 256 * 4096 + y * 64;
  #pragma unroll
  for (int i = 0; i < 16; ++i) {
    int chunk = i * 256 + t;
    int c = chunk >> 4;
    int q = chunk & 15;
    fx4 v = *(const fx4*)(src + (long)c * 4096 + q * 4);
    #pragma unroll
    for (int j = 0; j < 4; ++j) Af[axc(q * 4 + j, c)] = v[j];
  }
  __syncthreads();

  fx4 acc[4][4] = {};
  const short* Bb = W1bf + (long)(wv * 64 + li) * 256 + lg * 8;
  for (int c0 = 0; c0 < 256; c0 += 32) {
    bfx8 af[4], bfr[4];
    #pragma unroll
    for (int mi = 0; mi < 4; ++mi) {
      int p = mi * 16 + li;
      fx4 lo = *(const fx4*)(&Af[axc(p, c0 + lg * 8)]);
      fx4 hi = *(const fx4*)(&Af[axc(p, c0 + lg * 8 + 4)]);
      bfx8 tt;
      tt[0] = f2bf(lo[0]); tt[1] = f2bf(lo[1]); tt[2] = f2bf(lo[2]); tt[3] = f2bf(lo[3]);
      tt[4] = f2bf(hi[0]); tt[5] = f2bf(hi[1]); tt[6] = f2bf(hi[2]); tt[7] = f2bf(hi[3]);
      af[mi] = tt;
    }
    #pragma unroll
    for (int ni = 0; ni < 4; ++ni) bfr[ni] = *(const bfx8*)(Bb + ni * 16 * 256 + c0);
    #pragma unroll
    for (int mi = 0; mi < 4; ++mi)
      #pragma unroll
      for (int ni = 0; ni < 4; ++ni) MFMA16(acc[mi][ni], af[mi], bfr[ni]);
  }

  #pragma unroll
  for (int mi = 0; mi < 4; ++mi)
    #pragma unroll
    for (int ni = 0; ni < 4; ++ni) {
      int col = wv * 64 + ni * 16 + li;
      float bias = b1[col];
      #pragma unroll
      for (int r = 0; r < 4; ++r) {
        int x = mi * 16 + 4 * lg + r;
        dstP[(long)x * 256 + col] = f2bf(gelu_f(acc[mi][ni][r] + bias));
      }
    }
}

// ---------------- 128x128 MFMA GEMM body (m97 structure) ----------------
struct GemmP {
  const short* A; const short* B; void* O;
  const float* biasN; const float* biasM; const float* rowbias;
  long lda, ldb, ldo, sA, sB, sO;
  int M, N, K, outF32, act, padHW;
  int aShift;
  long sBN, sBM;
};

DEV void gemm_body(const GemmP& g, int bx, int by, int bz) {
  __shared__ short As[128 * 32];
  __shared__ short Bs[128 * 32];
  const int lane = threadIdx.x & 63, wv = threadIdx.x >> 6;
  const int wm = wv >> 1, wn = wv & 1;
  const int lg = lane >> 4, li = lane & 15;
  const int m0 = by * 128, n0 = bx * 128, z = bz;
  const short* A = g.A + (long)z * g.sA + (long)(n0 >> 8) * g.aShift;
  const short* B = g.B + (long)z * g.sB;
  const int srow = wv * 16 + (lane >> 2);
  const int scol = (lane & 3) * 8;
  const short* pA0 = A + (long)(m0 + srow) * g.lda + scol;
  const short* pA1 = A + (long)(m0 + 64 + srow) * g.lda + scol;
  const short* pB0 = B + (long)(n0 + srow) * g.ldb + scol;
  const short* pB1 = B + (long)(n0 + 64 + srow) * g.ldb + scol;
  short* ldsA = As + wv * 512;
  short* ldsB = Bs + wv * 512;
  const short* aRd = As + (wm * 64 + li) * 32 + lg * 8;
  const short* bRd = Bs + (wn * 64 + li) * 32 + lg * 8;

  fx4 acc[4][4] = {};
  for (int kc = 0; kc < g.K; kc += 32) {
    gl_lds16(pA0 + kc, ldsA);
    gl_lds16(pA1 + kc, ldsA + 2048);
    gl_lds16(pB0 + kc, ldsB);
    gl_lds16(pB1 + kc, ldsB + 2048);
    __syncthreads();
    bfx8 af[4], bf[4];
    #pragma unroll
    for (int mi = 0; mi < 4; ++mi) af[mi] = *(const bfx8*)(aRd + mi * 16 * 32);
    #pragma unroll
    for (int ni = 0; ni < 4; ++ni) bf[ni] = *(const bfx8*)(bRd + ni * 16 * 32);
    #pragma unroll
    for (int mi = 0; mi < 4; ++mi)
      #pragma unroll
      for (int ni = 0; ni < 4; ++ni)
        MFMA16(acc[mi][ni], af[mi], bf[ni]);
    __syncthreads();
  }

  #pragma unroll
  for (int mi = 0; mi < 4; ++mi)
    #pragma unroll
    for (int ni = 0; ni < 4; ++ni) {
      int col = n0 + wn * 64 + ni * 16 + li;
      int rowb = m0 + wm * 64 + mi * 16 + 4 * lg;
      float bn = g.biasN ? g.biasN[(long)z * g.sBN + col] : 0.0f;
      #pragma unroll
      for (int r = 0; r < 4; ++r) {
        int row = rowb + r;
        float v = acc[mi][ni][r] + bn;
        if (g.biasM) v += g.biasM[(long)z * g.sBM + row];
        if (g.act == 1) v = gelu_f(v);
        long oidx = (long)z * g.sO + (long)row * g.ldo + col;
        if (g.outF32) ((float*)g.O)[oidx] = v;
        else ((short*)g.O)[oidx] = f2bf(v);
      }
    }
}

// packed qk-proj (ids 0..1023) + v-proj (ids 1024..1535), XCD-swizzled
__global__ __launch_bounds__(256) void projk(GemmP gq, GemmP gv) {
  int bid = (int)blockIdx.x;
  int id = (bid & 7) * 192 + (bid >> 3);
  if (id < 1024) {
    int z = id >> 7, r = id & 127;
    gemm_body(gq, r & 3, r >> 2, z);
  } else {
    int j = id - 1024;
    int z = j >> 6, r = j & 63;
    gemm_body(gv, r & 31, r >> 5, z);
  }
}

// ---------------- conv2 3x3 implicit GEMM, BK=64 + fused GN stats, XCD-swizzled, 4-way split ----------------
__global__ __launch_bounds__(256) void conv2g(const short* xP, const short* W2t,
                                              const float* b2, short* qkv, float* stats, int wbase) {
  __shared__ short As[2 * 128 * 32];
  __shared__ short Bs[2 * 128 * 32];
  __shared__ float red[4][4];
  const int lane = threadIdx.x & 63, wv = threadIdx.x >> 6;
  const int wm = wv >> 1, wn = wv & 1;
  const int lg = lane >> 4, li = lane & 15;
  const int w = wbase + (((int)blockIdx.x & 7) * 48 + ((int)blockIdx.x >> 3));
  const int n0 = (w % 6) * 128;
  const int by = w / 6;
  const int b = by >> 5, ypair = by & 31;
  const short* xPb = xP + (long)b * 66 * 66 * 256;

  const int srow = wv * 16 + (lane >> 2);
  const int scol = (lane & 3) * 8;
  long baseA[2], baseB[2];
  #pragma unroll
  for (int j = 0; j < 2; ++j) {
    int r = j * 64 + srow;
    int yy = 2 * ypair + (r >> 6);
    int x = r & 63;
    baseA[j] = ((long)yy * 66 + x) * 256 + scol;
    baseB[j] = (long)(n0 + r) * 256 + scol;
  }
  short* ldsA = As + wv * 512;
  short* ldsB = Bs + wv * 512;
  const short* aRd = As + (wm * 64 + li) * 32 + lg * 8;
  const short* bRd = Bs + (wn * 64 + li) * 32 + lg * 8;

  fx4 acc[4][4] = {};
  for (int ks = 0; ks < 36; ++ks) {
    int tap = ks >> 2;
    int c0 = (ks & 3) * 64;
    int dy = tap / 3, dx = tap - dy * 3;
    long aoff = (long)(dy * 66 + dx) * 256 + c0;
    long boff = (long)tap * (768 * 256) + c0;
    gl_lds16(xPb + baseA[0] + aoff, ldsA);
    gl_lds16(xPb + baseA[1] + aoff, ldsA + 2048);
    gl_lds16(xPb + baseA[0] + aoff + 32, ldsA + 4096);
    gl_lds16(xPb + baseA[1] + aoff + 32, ldsA + 6144);
    gl_lds16(W2t + baseB[0] + boff, ldsB);
    gl_lds16(W2t + baseB[1] + boff, ldsB + 2048);
    gl_lds16(W2t + baseB[0] + boff + 32, ldsB + 4096);
    gl_lds16(W2t + baseB[1] + boff + 32, ldsB + 6144);
    __syncthreads();
    #pragma unroll
    for (int kk = 0; kk < 2; ++kk) {
      bfx8 af[4], bf[4];
      #pragma unroll
      for (int mi = 0; mi < 4; ++mi) af[mi] = *(const bfx8*)(aRd + kk * 4096 + mi * 16 * 32);
      #pragma unroll
      for (int ni = 0; ni < 4; ++ni) bf[ni] = *(const bfx8*)(bRd + kk * 4096 + ni * 16 * 32);
      #pragma unroll
      for (int mi = 0; mi < 4; ++mi)
        #pragma unroll
        for (int ni = 0; ni < 4; ++ni)
          MFMA16(acc[mi][ni], af[mi], bf[ni]);
    }
    __syncthreads();
  }

  const int g0 = n0 / 192;
  const int bnd = (g0 + 1) * 192;
  float sA = 0.0f, s2A = 0.0f, sB = 0.0f, s2B = 0.0f;
  const long prow0 = (long)b * 4096 + (long)ypair * 128 + wm * 64 + 4 * lg;
  #pragma unroll
  for (int ni = 0; ni < 4; ++ni) {
    int col = n0 + wn * 64 + ni * 16 + li;
    float bias = b2[col];
    bool inA = (col < bnd);
    #pragma unroll
    for (int mi = 0; mi < 4; ++mi) {
      long rb = prow0 + mi * 16;
      #pragma unroll
      for (int r = 0; r < 4; ++r) {
        float v = acc[mi][ni][r] + bias;
        if (inA) { sA += v; s2A += v * v; } else { sB += v; s2B += v * v; }
        qkv[(rb + r) * 768 + col] = f2bf(v);
      }
    }
  }
  #pragma unroll
  for (int off = 1; off < 64; off <<= 1) {
    sA += __shfl_xor(sA, off);  s2A += __shfl_xor(s2A, off);
    sB += __shfl_xor(sB, off);  s2B += __shfl_xor(s2B, off);
  }
  if (lane == 0) { red[wv][0] = sA; red[wv][1] = s2A; red[wv][2] = sB; red[wv][3] = s2B; }
  __syncthreads();
  if (threadIdx.x == 0) {
    float a1 = red[0][0] + red[1][0] + red[2][0] + red[3][0];
    float a2 = red[0][1] + red[1][1] + red[2][1] + red[3][1];
    atomicAdd(&stats[(b * 4 + g0) * 2], a1);
    atomicAdd(&stats[(b * 4 + g0) * 2 + 1], a2);
    if (bnd < n0 + 128) {
      float b1s = red[0][2] + red[1][2] + red[2][2] + red[3][2];
      float b2s = red[0][3] + red[1][3] + red[2][3] + red[3][3];
      atomicAdd(&stats[(b * 4 + g0 + 1) * 2], b1s);
      atomicAdd(&stats[(b * 4 + g0 + 1) * 2 + 1], b2s);
    }
  }
}

// fold GN affine into per-batch projection weights (stats finalized inline; gn_fin removed)
__global__ __launch_bounds__(256) void gn_fold(const float* stats, const float* gnw, const float* gnb,
                                               const float* inw, const float* inb,
                                               short* Wf, float* bfold) {
  const int lane = threadIdx.x & 63, wv = threadIdx.x >> 6;
  const int row = blockIdx.x * 4 + wv;
  const int b = row / 768, j = row - b * 768;
  const int cb = (j >> 8) << 8;
  const float nrm = 1.0f / (192.0f * 4096.0f);
  float part = 0.0f;
  #pragma unroll
  for (int i = 0; i < 4; ++i) {
    int c = lane + 64 * i;
    int cg = cb + c;
    int grp = cg / 192;
    float s1 = stats[(b * 4 + grp) * 2];
    float s2 = stats[(b * 4 + grp) * 2 + 1];
    float mu = s1 * nrm;
    float var = s2 * nrm - mu * mu;
    float rs = rsqrtf(var + 1e-5f);
    float s = rs * gnw[cg];
    float t = gnb[cg] - mu * s;
    float wv_ = inw[(long)j * 256 + c];
    Wf[(long)row * 256 + c] = f2bf(wv_ * s);
    part += t * wv_;
  }
  #pragma unroll
  for (int off = 1; off < 64; off <<= 1) part += __shfl_xor(part, off);
  if (lane == 0) bfold[row] = inb[j] + part;
}

// ---------------- text path: tmean -> tfb -> K/V per batch ----------------
__global__ __launch_bounds__(256) void globk_txt(const short* Tbf, const short* Wtxt,
                                                 const short* Wqkv, const float* tb,
                                                 const float* inb, float* khv, float* vhv) {
  __shared__ float tmean_s[4][512];
  __shared__ float tfb_s[4][256];
  const int t = threadIdx.x;
  const int b = blockIdx.x;
  {
    int key = t >> 6, d0 = (t & 63) * 8;
    float s[8] = {};
    const short* src = Tbf + ((long)(b * 64 + key * 16)) * 512 + d0;
    for (int i = 0; i < 16; ++i) {
      bfx8 v = *(const bfx8*)(src + i * 512);
      #pragma unroll
      for (int j = 0; j < 8; ++j) s[j] += bf2f(v[j]);
    }
    #pragma unroll
    for (int j = 0; j < 8; ++j) tmean_s[key][d0 + j] = s[j] * (1.0f / 16.0f);
  }
  __syncthreads();
  {
    int n = t;
    float a0 = 0, a1 = 0, a2 = 0, a3 = 0;
    const short* wr = Wtxt + (long)n * 512;
    for (int d = 0; d < 512; d += 8) {
      bfx8 w = *(const bfx8*)(wr + d);
      #pragma unroll
      for (int j = 0; j < 8; ++j) {
        float wf = bf2f(w[j]);
        a0 += tmean_s[0][d + j] * wf;
        a1 += tmean_s[1][d + j] * wf;
        a2 += tmean_s[2][d + j] * wf;
        a3 += tmean_s[3][d + j] * wf;
      }
    }
    float bias = tb[n];
    tfb_s[0][n] = a0 + bias; tfb_s[1][n] = a1 + bias;
    tfb_s[2][n] = a2 + bias; tfb_s[3][n] = a3 + bias;
  }
  __syncthreads();
  {
    int n = t;
    const short* wk = Wqkv + (long)(256 + n) * 256;
    const short* wvp = Wqkv + (long)(512 + n) * 256;
    float k0=0,k1=0,k2=0,k3=0,v0=0,v1=0,v2=0,v3=0;
    for (int d = 0; d < 256; d += 8) {
      bfx8 wkv = *(const bfx8*)(wk + d);
      bfx8 wvv = *(const bfx8*)(wvp + d);
      #pragma unroll
      for (int j = 0; j < 8; ++j) {
        float f0 = tfb_s[0][d+j], f1 = tfb_s[1][d+j], f2 = tfb_s[2][d+j], f3 = tfb_s[3][d+j];
        float kw = bf2f(wkv[j]), vw = bf2f(wvv[j]);
        k0 += f0*kw; k1 += f1*kw; k2 += f2*kw; k3 += f3*kw;
        v0 += f0*vw; v1 += f1*vw; v2 += f2*vw; v3 += f3*vw;
      }
    }
    float bk = inb[256+n], bv = inb[512+n];
    khv[(b*4+0)*256+n]=k0+bk; khv[(b*4+1)*256+n]=k1+bk;
    khv[(b*4+2)*256+n]=k2+bk; khv[(b*4+3)*256+n]=k3+bk;
    vhv[(b*4+0)*256+n]=v0+bv; vhv[(b*4+1)*256+n]=v1+bv;
    vhv[(b*4+2)*256+n]=v2+bv; vhv[(b*4+3)*256+n]=v3+bv;
  }
}

// ---------------- MEGA: local attention + global chain + ep1 + ep2 -> out ----------------
__global__ __launch_bounds__(256) void attn_mega(
    const short* qk, const short* vhT, const float* khv, const float* vhv,
    const short* Wo, const short* Wqkv, const short* Wep1, const short* Wcomb, const short* Wep2,
    const float* ob, const float* inb, const float* ebc, const float* e2b,
    float* out) {
  __shared__ short Pl[4 * 64 * 72];
  __shared__ float vecA[256], vecB[256], vecG[256];
  __shared__ float scb[16], pb[16];
  const int t = threadIdx.x;
  const int lane = t & 63, h = t >> 6;
  const int lg = lane >> 4, li = lane & 15;
  const int bw = blockIdx.x;
  const int b = bw >> 6, wY = bw & 63;
  const long p0 = (long)bw * 64;

  bfx8 qf[4][2], kf[4][2];
  #pragma unroll
  for (int mi = 0; mi < 4; ++mi)
    #pragma unroll
    for (int ks = 0; ks < 2; ++ks) {
      qf[mi][ks] = *(const bfx8*)(qk + (p0 + 16 * mi + li) * 512 + h * 64 + 32 * ks + 8 * lg);
      kf[mi][ks] = *(const bfx8*)(qk + (p0 + 16 * mi + li) * 512 + 256 + h * 64 + 32 * ks + 8 * lg);
    }
  fx4 s[4][4] = {};
  #pragma unroll
  for (int mi = 0; mi < 4; ++mi)
    #pragma unroll
    for (int ni = 0; ni < 4; ++ni) {
      MFMA16(s[mi][ni], qf[mi][0], kf[ni][0]);
      MFMA16(s[mi][ni], qf[mi][1], kf[ni][1]);
    }
  #pragma unroll
  for (int mi = 0; mi < 4; ++mi)
    #pragma unroll
    for (int ni = 0; ni < 4; ++ni) s[mi][ni] *= 0.125f;

  #pragma unroll
  for (int mi = 0; mi < 4; ++mi)
    #pragma unroll
    for (int r = 0; r < 4; ++r) {
      float mx = fmaxf(fmaxf(s[mi][0][r], s[mi][1][r]), fmaxf(s[mi][2][r], s[mi][3][r]));
      for (int off = 1; off < 16; off <<= 1) mx = fmaxf(mx, __shfl_xor(mx, off));
      float e[4];
      float sum = 0.0f;
      #pragma unroll
      for (int ni = 0; ni < 4; ++ni) { e[ni] = expf(s[mi][ni][r] - mx); sum += e[ni]; }
      for (int off = 1; off < 16; off <<= 1) sum += __shfl_xor(sum, off);
      float inv = 1.0f / sum;
      int row = h * 64 + 16 * mi + 4 * lg + r;
      #pragma unroll
      for (int ni = 0; ni < 4; ++ni) Pl[row * 72 + 16 * ni + li] = f2bf(e[ni] * inv);
    }
  __syncthreads();

  fx4 o[4][4] = {};
  #pragma unroll
  for (int ks = 0; ks < 2; ++ks) {
    bfx8 pf[4], vf[4];
    #pragma unroll
    for (int mi = 0; mi < 4; ++mi)
      pf[mi] = *(const bfx8*)(&Pl[(h * 64 + 16 * mi + li) * 72 + 32 * ks + 8 * lg]);
    #pragma unroll
    for (int ni = 0; ni < 4; ++ni)
      vf[ni] = *(const bfx8*)(vhT + ((long)(b * 256 + h * 64 + 16 * ni + li)) * 4096 + wY * 64 + 32 * ks + 8 * lg);
    #pragma unroll
    for (int mi = 0; mi < 4; ++mi)
      #pragma unroll
      for (int ni = 0; ni < 4; ++ni) MFMA16(o[mi][ni], pf[mi], vf[ni]);
  }

  #pragma unroll
  for (int ni = 0; ni < 4; ++ni) {
    float s2 = 0.0f;
    #pragma unroll
    for (int mi = 0; mi < 4; ++mi)
      #pragma unroll
      for (int r = 0; r < 4; ++r) s2 += o[mi][ni][r];
    s2 += __shfl_xor(s2, 16);
    s2 += __shfl_xor(s2, 32);
    if (lg == 0) vecA[h * 64 + 16 * ni + li] = s2 * (1.0f / 64.0f);
  }
  __syncthreads();

  short* obuf = Pl;
  #pragma unroll
  for (int mi = 0; mi < 4; ++mi)
    #pragma unroll
    for (int ni = 0; ni < 4; ++ni)
      #pragma unroll
      for (int r = 0; r < 4; ++r)
        obuf[(16 * mi + 4 * lg + r) * 264 + h * 64 + 16 * ni + li] = f2bf(o[mi][ni][r]);

  { // gq = vecA @ Wo^T + ob -> vecB
    float sum = 0.0f;
    const short* wr = Wo + (long)t * 256;
    for (int d = 0; d < 256; d += 8) {
      bfx8 w8 = *(const bfx8*)(wr + d);
      #pragma unroll
      for (int j = 0; j < 8; ++j) sum += vecA[d + j] * bf2f(w8[j]);
    }
    vecB[t] = sum + ob[t];
  }
  __syncthreads();
  { // qhg = vecB @ Wq^T + inb -> vecG
    float sum = 0.0f;
    const short* wr = Wqkv + (long)t * 256;
    for (int d = 0; d < 256; d += 8) {
      bfx8 w8 = *(const bfx8*)(wr + d);
      #pragma unroll
      for (int j = 0; j < 8; ++j) sum += vecB[d + j] * bf2f(w8[j]);
    }
    vecG[t] = sum + inb[t];
  }
  __syncthreads();
  if (t < 16) {
    int key = t & 3, hh = t >> 2;
    float sum = 0.0f;
    const float* kr = khv + (long)(b * 4 + key) * 256 + hh * 64;
    for (int d = 0; d < 64; ++d) sum += vecG[hh * 64 + d] * kr[d];
    scb[hh * 4 + key] = sum * 0.125f;
  }
  __syncthreads();
  if (t < 4) {
    float s0 = scb[t*4], s1 = scb[t*4+1], s2 = scb[t*4+2], s3 = scb[t*4+3];
    float mx = fmaxf(fmaxf(s0, s1), fmaxf(s2, s3));
    float e0 = expf(s0-mx), e1 = expf(s1-mx), e2 = expf(s2-mx), e3 = expf(s3-mx);
    float inv = 1.0f / (e0 + e1 + e2 + e3);
    pb[t*4] = e0*inv; pb[t*4+1] = e1*inv; pb[t*4+2] = e2*inv; pb[t*4+3] = e3*inv;
  }
  __syncthreads();
  {
    int hh = t >> 6;
    long base = (long)(b * 4) * 256 + t;
    vecB[t] = pb[hh*4]   * vhv[base] +
              pb[hh*4+1] * vhv[base + 256] +
              pb[hh*4+2] * vhv[base + 512] +
              pb[hh*4+3] * vhv[base + 768];
  }
  __syncthreads();
  { // glb = vecB @ Wo^T + ob -> vecA
    float sum = 0.0f;
    const short* wr = Wo + (long)t * 256;
    for (int d = 0; d < 256; d += 8) {
      bfx8 w8 = *(const bfx8*)(wr + d);
      #pragma unroll
      for (int j = 0; j < 8; ++j) sum += vecB[d + j] * bf2f(w8[j]);
    }
    vecA[t] = sum + ob[t];
  }
  __syncthreads();
  { // gcon = vecA @ E1b^T + ebc -> vecG
    float sum = 0.0f;
    const short* wr = Wep1 + (long)t * 512 + 256;
    for (int d = 0; d < 256; d += 8) {
      bfx8 w8 = *(const bfx8*)(wr + d);
      #pragma unroll
      for (int j = 0; j < 8; ++j) sum += vecA[d + j] * bf2f(w8[j]);
    }
    vecG[t] = sum + ebc[t];
  }
  __syncthreads();

  fx4 hacc[4][4] = {};
  const short* bR2 = Wcomb + (long)(h * 64 + li) * 256 + lg * 8;
  for (int kc = 0; kc < 256; kc += 32) {
    bfx8 af[4], bf[4];
    #pragma unroll
    for (int mi = 0; mi < 4; ++mi)
      af[mi] = *(const bfx8*)(obuf + (mi * 16 + li) * 264 + kc + lg * 8);
    #pragma unroll
    for (int ni = 0; ni < 4; ++ni) bf[ni] = *(const bfx8*)(bR2 + (long)ni * 16 * 256 + kc);
    #pragma unroll
    for (int mi = 0; mi < 4; ++mi)
      #pragma unroll
      for (int ni = 0; ni < 4; ++ni) MFMA16(hacc[mi][ni], af[mi], bf[ni]);
  }
  __syncthreads();
  #pragma unroll
  for (int mi = 0; mi < 4; ++mi)
    #pragma unroll
    for (int ni = 0; ni < 4; ++ni) {
      int col = h * 64 + ni * 16 + li;
      #pragma unroll
      for (int r = 0; r < 4; ++r) {
        int row = mi * 16 + 4 * lg + r;
        obuf[row * 264 + col] = f2bf(gelu_f(hacc[mi][ni][r] + vecG[col]));
      }
    }
  __syncthreads();

  {
    int row = t >> 2, eg = (t & 3) * 4;
    const short* hr = obuf + row * 264;
    float a0 = e2b[eg], a1 = e2b[eg+1], a2 = e2b[eg+2], a3 = e2b[eg+3];
    const short* w0 = Wep2 + (long)eg * 256;
    for (int k = 0; k < 256; k += 8) {
      bfx8 hv = *(const bfx8*)(hr + k);
      bfx8 wv0 = *(const bfx8*)(w0 + k);
      bfx8 wv1 = *(const bfx8*)(w0 + 256 + k);
      bfx8 wv2 = *(const bfx8*)(w0 + 512 + k);
      bfx8 wv3 = *(const bfx8*)(w0 + 768 + k);
      #pragma unroll
      for (int j = 0; j < 8; ++j) {
        float hf = bf2f(hv[j]);
        a0 += hf * bf2f(wv0[j]);
        a1 += hf * bf2f(wv1[j]);
        a2 += hf * bf2f(wv2[j]);
        a3 += hf * bf2f(wv3[j]);
      }
    }
    float* orow = out + (p0 + row) * 16 + eg;
    orow[0] = 1.0f / (1.0f + expf(-a0));
    orow[1] = 1.0f / (1.0f + expf(-a1));
    orow[2] = 1.0f / (1.0f + expf(-a2));
    orow[3] = 1.0f / (1.0f + expf(-a3));
  }
}

// ---------------- host ----------------
extern "C" void kernel_launch(void* const* d_in, const int* in_sizes, int n_in,
                              void* d_out, int out_size, void* d_ws, size_t ws_size,
                              hipStream_t stream) {
  (void)in_sizes; (void)n_in; (void)out_size; (void)ws_size;
  const float* fm  = (const float*)d_in[0];
  const float* txt = (const float*)d_in[1];
  const float* w1  = (const float*)d_in[2];
  const float* b1  = (const float*)d_in[3];
  const float* w2  = (const float*)d_in[4];
  const float* b2  = (const float*)d_in[5];
  const float* gnw = (const float*)d_in[6];
  const float* gnb = (const float*)d_in[7];
  const float* inw = (const float*)d_in[8];
  const float* inb = (const float*)d_in[9];
  const float* ow  = (const float*)d_in[10];
  const float* ob  = (const float*)d_in[11];
  const float* tw  = (const float*)d_in[12];
  const float* tb  = (const float*)d_in[13];
  const float* e1w = (const float*)d_in[14];
  const float* e1b = (const float*)d_in[15];
  const float* e2w = (const float*)d_in[16];
  const float* e2b = (const float*)d_in[17];
  float* out = (float*)d_out;

  char* base = (char*)d_ws;
  size_t off = 0;
  auto alloc = [&](size_t bytes) -> char* {
    char* r = base + off;
    off = (off + bytes + 255) & ~(size_t)255;
    return r;
  };
  short* W1bf = (short*)alloc(256 * 256 * 2);
  short* W2t  = (short*)alloc((size_t)9 * 768 * 256 * 2);
  short* Wqkv = (short*)alloc(768 * 256 * 2);
  short* Wo   = (short*)alloc(256 * 256 * 2);
  short* Wcomb= (short*)alloc(256 * 256 * 2);
  float* ebc  = (float*)alloc(256 * 4);
  short* Wtxt = (short*)alloc(256 * 512 * 2);
  short* Wep1 = (short*)alloc(256 * 512 * 2);
  short* Wep2 = (short*)alloc(16 * 256 * 2);
  short* Tbf  = (short*)alloc((size_t)8 * 64 * 512 * 2);
  short* xP   = (short*)alloc((size_t)8 * 66 * 66 * 256 * 2);
  short* qkv  = (short*)alloc((size_t)8 * 4096 * 768 * 2);
  float* stats= (float*)alloc(64 * 4);
  short* Wf   = (short*)alloc((size_t)8 * 768 * 256 * 2);
  float* bfold= (float*)alloc((size_t)8 * 768 * 4);
  short* qk   = (short*)alloc((size_t)32768 * 512 * 2);
  short* vhT  = (short*)alloc((size_t)8 * 4096 * 256 * 2);
  float* khv  = (float*)alloc(8 * 4 * 256 * 4);
  float* vhv  = (float*)alloc(8 * 4 * 256 * 4);

  hipMemsetAsync(stats, 0, 64 * 4, stream);

  CvtArgs ca;
  ca.s[0] = {w1,  W1bf, 256 * 256};
  ca.s[1] = {inw, Wqkv, 768 * 256};
  ca.s[2] = {ow,  Wo,   256 * 256};
  ca.s[3] = {tw,  Wtxt, 256 * 512};
  ca.s[4] = {e1w, Wep1, 256 * 512};
  ca.s[5] = {e2w, Wep2, 16 * 256};
  ca.s[6] = {txt, Tbf,  8 * 64 * 512};
  cvt_multi<<<dim3(128, 7), 256, 0, stream>>>(ca);
  cvt_conv2w<<<768, 256, 0, stream>>>(w2, W2t);
  ebc2<<<256, 64, 0, stream>>>(e1w, e1b, ob, ebc);
  globk_txt<<<8, 256, 0, stream>>>(Tbf, Wtxt, Wqkv, tb, inb, khv, vhv);
  wcombk<<<dim3(4, 4), 256, 0, stream>>>(ow, Wep1, Wcomb);

  tc1<<<512, 256, 0, stream>>>(fm, W1bf, b1, xP);

  conv2g<<<384, 256, 0, stream>>>(xP, W2t, b2, qkv, stats, 0);
  conv2g<<<384, 256, 0, stream>>>(xP, W2t, b2, qkv, stats, 384);
  conv2g<<<384, 256, 0, stream>>>(xP, W2t, b2, qkv, stats, 768);
  conv2g<<<384, 256, 0, stream>>>(xP, W2t, b2, qkv, stats, 1152);

  gn_fold<<<1536, 256, 0, stream>>>(stats, gnw, gnb, inw, inb, Wf, bfold);

  { // packed qk + v projections
    GemmP gq{};
    gq.A = qkv; gq.lda = 768; gq.sA = 4096L * 768;
    gq.B = Wf; gq.ldb = 256; gq.sB = 768L * 256;
    gq.O = qk; gq.ldo = 512; gq.sO = 4096L * 512;
    gq.biasN = bfold; gq.sBN = 768;
    gq.aShift = 256;
    gq.M = 4096; gq.N = 512; gq.K = 256;
    GemmP gv{};
    gv.A = Wf + 512 * 256; gv.lda = 256; gv.sA = 768L * 256;
    gv.B = qkv + 512; gv.ldb = 768; gv.sB = 4096L * 768;
    gv.O = vhT; gv.ldo = 4096; gv.sO = 256L * 4096;
    gv.biasM = bfold + 512; gv.sBM = 768;
    gv.M = 256; gv.N = 4096; gv.K = 256;
    projk<<<1536, 256, 0, stream>>>(gq, gv);
  }

  attn_mega<<<512, 256, 0, stream>>>(qk, vhT, khv, vhv,
                                     Wo, Wqkv, Wep1, Wcomb, Wep2,
                                     ob, inb, ebc, e2b, out);
}

// Round 10
// 328.453 us; speedup vs baseline: 1.3551x; 1.3551x over previous
//
#include <hip/hip_runtime.h>

#define DEV __device__ __forceinline__

typedef __attribute__((ext_vector_type(8))) short bfx8;
typedef __attribute__((ext_vector_type(4))) float fx4;

typedef __attribute__((address_space(3))) unsigned int as3_u32;
typedef const __attribute__((address_space(1))) unsigned int as1_u32c;

DEV void gl_lds16(const void* g, const void* l) {
  __builtin_amdgcn_global_load_lds((as1_u32c*)(unsigned long long)g,
                                   (as3_u32*)(unsigned long long)l, 16, 0, 0);
}

DEV short f2bf(float f) {
  unsigned u = __float_as_uint(f);
  u += 0x7fffu + ((u >> 16) & 1u);
  return (short)(u >> 16);
}
DEV float bf2f(short s) {
  return __uint_as_float(((unsigned)(unsigned short)s) << 16);
}
DEV float gelu_f(float x) { return 0.5f * x * (1.0f + erff(x * 0.70710678118654752f)); }

#define MFMA16(acc, a, b) (acc) = __builtin_amdgcn_mfma_f32_16x16x32_bf16((a), (b), (acc), 0, 0, 0)

// ---------------- conversions ----------------
struct CvtSeg { const float* src; short* dst; int n; };
struct CvtArgs { CvtSeg s[7]; };

__global__ __launch_bounds__(256) void cvt_multi(CvtArgs a) {
  CvtSeg s = a.s[blockIdx.y];
  int i = ((int)blockIdx.x * 256 + (int)threadIdx.x) * 8;
  if (i >= s.n) return;
  bfx8 o;
  #pragma unroll
  for (int j = 0; j < 8; ++j) o[j] = f2bf(s.src[i + j]);
  *(bfx8*)(s.dst + i) = o;
}

// conv2_w (768,256,3,3) -> W2t [tap][o][c]
__global__ __launch_bounds__(256) void cvt_conv2w(const float* src, short* dst) {
  int oc = (int)blockIdx.x * 256 + (int)threadIdx.x;
  const float* s = src + (long)oc * 9;
  float t[9];
  #pragma unroll
  for (int j = 0; j < 9; ++j) t[j] = s[j];
  #pragma unroll
  for (int tap = 0; tap < 9; ++tap)
    dst[(long)tap * (768 * 256) + oc] = f2bf(t[tap]);
}

// ebc[n] = e1b[n] + sum_c ob[c]*e1w[n][c]
__global__ __launch_bounds__(64) void ebc2(const float* e1w, const float* e1b, const float* ob, float* ebc) {
  int n = blockIdx.x, lane = threadIdx.x;
  float s = 0.0f;
  #pragma unroll
  for (int i = 0; i < 4; ++i) {
    int c = lane + 64 * i;
    s += ob[c] * e1w[(long)n * 512 + c];
  }
  #pragma unroll
  for (int off = 1; off < 64; off <<= 1) s += __shfl_xor(s, off);
  if (lane == 0) ebc[n] = e1b[n] + s;
}

// fused: Wcomb[m][d] = sum_c E1a[m][c] * ow[c][d]  (in-kernel transpose of ow)
__global__ __launch_bounds__(256) void wcombk(const float* ow, const short* Wep1, short* Wcomb) {
  __shared__ short Bt[64 * 264];
  const int t = threadIdx.x;
  const int lane = t & 63, w = t >> 6;
  const int lg = lane >> 4, li = lane & 15;
  const int m0 = blockIdx.y * 64, n0 = blockIdx.x * 64;
  for (int idx = t; idx < 64 * 256; idx += 256) {
    int c = idx >> 6, d = idx & 63;
    Bt[d * 264 + c] = f2bf(ow[(long)c * 256 + n0 + d]);
  }
  __syncthreads();
  fx4 acc[4] = {};
  const short* aR = Wep1 + (long)(m0 + w * 16 + li) * 512 + lg * 8;
  for (int kc = 0; kc < 256; kc += 32) {
    bfx8 a = *(const bfx8*)(aR + kc);
    #pragma unroll
    for (int ni = 0; ni < 4; ++ni) {
      bfx8 bv = *(const bfx8*)(&Bt[(ni * 16 + li) * 264 + kc + lg * 8]);
      MFMA16(acc[ni], a, bv);
    }
  }
  #pragma unroll
  for (int ni = 0; ni < 4; ++ni)
    #pragma unroll
    for (int r = 0; r < 4; ++r)
      Wcomb[(long)(m0 + w * 16 + 4 * lg + r) * 256 + n0 + ni * 16 + li] = f2bf(acc[ni][r]);
}

// ---------------- fused transpose + conv1(1x1) + gelu (+ zero borders of xP) ----------------
DEV int axc(int p, int c) { return p * 260 + (c ^ (((p >> 2) & 7) << 2)); }

__global__ __launch_bounds__(256) void tc1(const float* fm, const short* W1bf,
                                           const float* b1, short* xP) {
  __shared__ float Af[64 * 260];
  const int lane = threadIdx.x & 63, wv = threadIdx.x >> 6;
  const int lg = lane >> 4, li = lane & 15;
  const int y = blockIdx.x & 63, b = blockIdx.x >> 6;
  const int t = threadIdx.x;
  short* dstP = xP + ((long)b * 66 * 66 + (long)(y + 1) * 66 + 1) * 256;
  const bfx8 z8 = {0, 0, 0, 0, 0, 0, 0, 0};

  if (t < 64) {
    if (t < 32) *(bfx8*)(dstP - 256 + t * 8) = z8;
    else        *(bfx8*)(dstP + 64 * 256 + (t - 32) * 8) = z8;
  }
  if (y == 0) {
    short* top = xP + (long)b * 66 * 66 * 256;
    for (int i = t; i < 2112; i += 256) *(bfx8*)(top + i * 8) = z8;
  }
  if (y == 63) {
    short* bot = xP + ((long)b * 66 * 66 + 65 * 66) * 256;
    for (int i = t; i < 2112; i += 256) *(bfx8*)(bot + i * 8) = z8;
  }

  const float* src = fm + (long)b * 256 * 4096 + y * 64;
  #pragma unroll
  for (int i = 0; i < 16; ++i) {
    int chunk = i * 256 + t;
    int c = chunk >> 4;
    int q = chunk & 15;
    fx4 v = *(const fx4*)(src + (long)c * 4096 + q * 4);
    #pragma unroll
    for (int j = 0; j < 4; ++j) Af[axc(q * 4 + j, c)] = v[j];
  }
  __syncthreads();

  fx4 acc[4][4] = {};
  const short* Bb = W1bf + (long)(wv * 64 + li) * 256 + lg * 8;
  for (int c0 = 0; c0 < 256; c0 += 32) {
    bfx8 af[4], bfr[4];
    #pragma unroll
    for (int mi = 0; mi < 4; ++mi) {
      int p = mi * 16 + li;
      fx4 lo = *(const fx4*)(&Af[axc(p, c0 + lg * 8)]);
      fx4 hi = *(const fx4*)(&Af[axc(p, c0 + lg * 8 + 4)]);
      bfx8 tt;
      tt[0] = f2bf(lo[0]); tt[1] = f2bf(lo[1]); tt[2] = f2bf(lo[2]); tt[3] = f2bf(lo[3]);
      tt[4] = f2bf(hi[0]); tt[5] = f2bf(hi[1]); tt[6] = f2bf(hi[2]); tt[7] = f2bf(hi[3]);
      af[mi] = tt;
    }
    #pragma unroll
    for (int ni = 0; ni < 4; ++ni) bfr[ni] = *(const bfx8*)(Bb + ni * 16 * 256 + c0);
    #pragma unroll
    for (int mi = 0; mi < 4; ++mi)
      #pragma unroll
      for (int ni = 0; ni < 4; ++ni) MFMA16(acc[mi][ni], af[mi], bfr[ni]);
  }

  #pragma unroll
  for (int mi = 0; mi < 4; ++mi)
    #pragma unroll
    for (int ni = 0; ni < 4; ++ni) {
      int col = wv * 64 + ni * 16 + li;
      float bias = b1[col];
      #pragma unroll
      for (int r = 0; r < 4; ++r) {
        int x = mi * 16 + 4 * lg + r;
        dstP[(long)x * 256 + col] = f2bf(gelu_f(acc[mi][ni][r] + bias));
      }
    }
}

// ---------------- 128x128 MFMA GEMM body (m97 structure) ----------------
struct GemmP {
  const short* A; const short* B; void* O;
  const float* biasN; const float* biasM; const float* rowbias;
  long lda, ldb, ldo, sA, sB, sO;
  int M, N, K, outF32, act, padHW;
  int aShift;
  long sBN, sBM;
};

DEV void gemm_body(const GemmP& g, int bx, int by, int bz) {
  __shared__ short As[128 * 32];
  __shared__ short Bs[128 * 32];
  const int lane = threadIdx.x & 63, wv = threadIdx.x >> 6;
  const int wm = wv >> 1, wn = wv & 1;
  const int lg = lane >> 4, li = lane & 15;
  const int m0 = by * 128, n0 = bx * 128, z = bz;
  const short* A = g.A + (long)z * g.sA + (long)(n0 >> 8) * g.aShift;
  const short* B = g.B + (long)z * g.sB;
  const int srow = wv * 16 + (lane >> 2);
  const int scol = (lane & 3) * 8;
  const short* pA0 = A + (long)(m0 + srow) * g.lda + scol;
  const short* pA1 = A + (long)(m0 + 64 + srow) * g.lda + scol;
  const short* pB0 = B + (long)(n0 + srow) * g.ldb + scol;
  const short* pB1 = B + (long)(n0 + 64 + srow) * g.ldb + scol;
  short* ldsA = As + wv * 512;
  short* ldsB = Bs + wv * 512;
  const short* aRd = As + (wm * 64 + li) * 32 + lg * 8;
  const short* bRd = Bs + (wn * 64 + li) * 32 + lg * 8;

  fx4 acc[4][4] = {};
  for (int kc = 0; kc < g.K; kc += 32) {
    gl_lds16(pA0 + kc, ldsA);
    gl_lds16(pA1 + kc, ldsA + 2048);
    gl_lds16(pB0 + kc, ldsB);
    gl_lds16(pB1 + kc, ldsB + 2048);
    __syncthreads();
    bfx8 af[4], bf[4];
    #pragma unroll
    for (int mi = 0; mi < 4; ++mi) af[mi] = *(const bfx8*)(aRd + mi * 16 * 32);
    #pragma unroll
    for (int ni = 0; ni < 4; ++ni) bf[ni] = *(const bfx8*)(bRd + ni * 16 * 32);
    #pragma unroll
    for (int mi = 0; mi < 4; ++mi)
      #pragma unroll
      for (int ni = 0; ni < 4; ++ni)
        MFMA16(acc[mi][ni], af[mi], bf[ni]);
    __syncthreads();
  }

  #pragma unroll
  for (int mi = 0; mi < 4; ++mi)
    #pragma unroll
    for (int ni = 0; ni < 4; ++ni) {
      int col = n0 + wn * 64 + ni * 16 + li;
      int rowb = m0 + wm * 64 + mi * 16 + 4 * lg;
      float bn = g.biasN ? g.biasN[(long)z * g.sBN + col] : 0.0f;
      #pragma unroll
      for (int r = 0; r < 4; ++r) {
        int row = rowb + r;
        float v = acc[mi][ni][r] + bn;
        if (g.biasM) v += g.biasM[(long)z * g.sBM + row];
        if (g.act == 1) v = gelu_f(v);
        long oidx = (long)z * g.sO + (long)row * g.ldo + col;
        if (g.outF32) ((float*)g.O)[oidx] = v;
        else ((short*)g.O)[oidx] = f2bf(v);
      }
    }
}

// packed qk-proj (ids 0..1023) + v-proj (ids 1024..1535), XCD-swizzled
__global__ __launch_bounds__(256) void projk(GemmP gq, GemmP gv) {
  int bid = (int)blockIdx.x;
  int id = (bid & 7) * 192 + (bid >> 3);
  if (id < 1024) {
    int z = id >> 7, r = id & 127;
    gemm_body(gq, r & 3, r >> 2, z);
  } else {
    int j = id - 1024;
    int z = j >> 6, r = j & 63;
    gemm_body(gv, r & 31, r >> 5, z);
  }
}

// ---------------- conv2 3x3 implicit GEMM, BK=64 + fused GN stats, XCD-swizzled (single dispatch) ----------------
__global__ __launch_bounds__(256) void conv2g(const short* xP, const short* W2t,
                                              const float* b2, short* qkv, float* stats) {
  __shared__ short As[2 * 128 * 32];
  __shared__ short Bs[2 * 128 * 32];
  __shared__ float red[4][4];
  const int lane = threadIdx.x & 63, wv = threadIdx.x >> 6;
  const int wm = wv >> 1, wn = wv & 1;
  const int lg = lane >> 4, li = lane & 15;
  const int w = ((int)blockIdx.x & 7) * 192 + ((int)blockIdx.x >> 3);
  const int n0 = (w % 6) * 128;
  const int by = w / 6;
  const int b = by >> 5, ypair = by & 31;
  const short* xPb = xP + (long)b * 66 * 66 * 256;

  const int srow = wv * 16 + (lane >> 2);
  const int scol = (lane & 3) * 8;
  long baseA[2], baseB[2];
  #pragma unroll
  for (int j = 0; j < 2; ++j) {
    int r = j * 64 + srow;
    int yy = 2 * ypair + (r >> 6);
    int x = r & 63;
    baseA[j] = ((long)yy * 66 + x) * 256 + scol;
    baseB[j] = (long)(n0 + r) * 256 + scol;
  }
  short* ldsA = As + wv * 512;
  short* ldsB = Bs + wv * 512;
  const short* aRd = As + (wm * 64 + li) * 32 + lg * 8;
  const short* bRd = Bs + (wn * 64 + li) * 32 + lg * 8;

  fx4 acc[4][4] = {};
  for (int ks = 0; ks < 36; ++ks) {
    int tap = ks >> 2;
    int c0 = (ks & 3) * 64;
    int dy = tap / 3, dx = tap - dy * 3;
    long aoff = (long)(dy * 66 + dx) * 256 + c0;
    long boff = (long)tap * (768 * 256) + c0;
    gl_lds16(xPb + baseA[0] + aoff, ldsA);
    gl_lds16(xPb + baseA[1] + aoff, ldsA + 2048);
    gl_lds16(xPb + baseA[0] + aoff + 32, ldsA + 4096);
    gl_lds16(xPb + baseA[1] + aoff + 32, ldsA + 6144);
    gl_lds16(W2t + baseB[0] + boff, ldsB);
    gl_lds16(W2t + baseB[1] + boff, ldsB + 2048);
    gl_lds16(W2t + baseB[0] + boff + 32, ldsB + 4096);
    gl_lds16(W2t + baseB[1] + boff + 32, ldsB + 6144);
    __syncthreads();
    #pragma unroll
    for (int kk = 0; kk < 2; ++kk) {
      bfx8 af[4], bf[4];
      #pragma unroll
      for (int mi = 0; mi < 4; ++mi) af[mi] = *(const bfx8*)(aRd + kk * 4096 + mi * 16 * 32);
      #pragma unroll
      for (int ni = 0; ni < 4; ++ni) bf[ni] = *(const bfx8*)(bRd + kk * 4096 + ni * 16 * 32);
      #pragma unroll
      for (int mi = 0; mi < 4; ++mi)
        #pragma unroll
        for (int ni = 0; ni < 4; ++ni)
          MFMA16(acc[mi][ni], af[mi], bf[ni]);
    }
    __syncthreads();
  }

  const int g0 = n0 / 192;
  const int bnd = (g0 + 1) * 192;
  float sA = 0.0f, s2A = 0.0f, sB = 0.0f, s2B = 0.0f;
  const long prow0 = (long)b * 4096 + (long)ypair * 128 + wm * 64 + 4 * lg;
  #pragma unroll
  for (int ni = 0; ni < 4; ++ni) {
    int col = n0 + wn * 64 + ni * 16 + li;
    float bias = b2[col];
    bool inA = (col < bnd);
    #pragma unroll
    for (int mi = 0; mi < 4; ++mi) {
      long rb = prow0 + mi * 16;
      #pragma unroll
      for (int r = 0; r < 4; ++r) {
        float v = acc[mi][ni][r] + bias;
        if (inA) { sA += v; s2A += v * v; } else { sB += v; s2B += v * v; }
        qkv[(rb + r) * 768 + col] = f2bf(v);
      }
    }
  }
  #pragma unroll
  for (int off = 1; off < 64; off <<= 1) {
    sA += __shfl_xor(sA, off);  s2A += __shfl_xor(s2A, off);
    sB += __shfl_xor(sB, off);  s2B += __shfl_xor(s2B, off);
  }
  if (lane == 0) { red[wv][0] = sA; red[wv][1] = s2A; red[wv][2] = sB; red[wv][3] = s2B; }
  __syncthreads();
  if (threadIdx.x == 0) {
    float a1 = red[0][0] + red[1][0] + red[2][0] + red[3][0];
    float a2 = red[0][1] + red[1][1] + red[2][1] + red[3][1];
    atomicAdd(&stats[(b * 4 + g0) * 2], a1);
    atomicAdd(&stats[(b * 4 + g0) * 2 + 1], a2);
    if (bnd < n0 + 128) {
      float b1s = red[0][2] + red[1][2] + red[2][2] + red[3][2];
      float b2s = red[0][3] + red[1][3] + red[2][3] + red[3][3];
      atomicAdd(&stats[(b * 4 + g0 + 1) * 2], b1s);
      atomicAdd(&stats[(b * 4 + g0 + 1) * 2 + 1], b2s);
    }
  }
}

// fold GN affine into per-batch projection weights (stats finalized inline)
__global__ __launch_bounds__(256) void gn_fold(const float* stats, const float* gnw, const float* gnb,
                                               const float* inw, const float* inb,
                                               short* Wf, float* bfold) {
  const int lane = threadIdx.x & 63, wv = threadIdx.x >> 6;
  const int row = blockIdx.x * 4 + wv;
  const int b = row / 768, j = row - b * 768;
  const int cb = (j >> 8) << 8;
  const float nrm = 1.0f / (192.0f * 4096.0f);
  float part = 0.0f;
  #pragma unroll
  for (int i = 0; i < 4; ++i) {
    int c = lane + 64 * i;
    int cg = cb + c;
    int grp = cg / 192;
    float s1 = stats[(b * 4 + grp) * 2];
    float s2 = stats[(b * 4 + grp) * 2 + 1];
    float mu = s1 * nrm;
    float var = s2 * nrm - mu * mu;
    float rs = rsqrtf(var + 1e-5f);
    float s = rs * gnw[cg];
    float t = gnb[cg] - mu * s;
    float wv_ = inw[(long)j * 256 + c];
    Wf[(long)row * 256 + c] = f2bf(wv_ * s);
    part += t * wv_;
  }
  #pragma unroll
  for (int off = 1; off < 64; off <<= 1) part += __shfl_xor(part, off);
  if (lane == 0) bfold[row] = inb[j] + part;
}

// ---------------- text path: tmean -> tfb -> K/V per batch ----------------
__global__ __launch_bounds__(256) void globk_txt(const short* Tbf, const short* Wtxt,
                                                 const short* Wqkv, const float* tb,
                                                 const float* inb, float* khv, float* vhv) {
  __shared__ float tmean_s[4][512];
  __shared__ float tfb_s[4][256];
  const int t = threadIdx.x;
  const int b = blockIdx.x;
  {
    int key = t >> 6, d0 = (t & 63) * 8;
    float s[8] = {};
    const short* src = Tbf + ((long)(b * 64 + key * 16)) * 512 + d0;
    for (int i = 0; i < 16; ++i) {
      bfx8 v = *(const bfx8*)(src + i * 512);
      #pragma unroll
      for (int j = 0; j < 8; ++j) s[j] += bf2f(v[j]);
    }
    #pragma unroll
    for (int j = 0; j < 8; ++j) tmean_s[key][d0 + j] = s[j] * (1.0f / 16.0f);
  }
  __syncthreads();
  {
    int n = t;
    float a0 = 0, a1 = 0, a2 = 0, a3 = 0;
    const short* wr = Wtxt + (long)n * 512;
    for (int d = 0; d < 512; d += 8) {
      bfx8 w = *(const bfx8*)(wr + d);
      #pragma unroll
      for (int j = 0; j < 8; ++j) {
        float wf = bf2f(w[j]);
        a0 += tmean_s[0][d + j] * wf;
        a1 += tmean_s[1][d + j] * wf;
        a2 += tmean_s[2][d + j] * wf;
        a3 += tmean_s[3][d + j] * wf;
      }
    }
    float bias = tb[n];
    tfb_s[0][n] = a0 + bias; tfb_s[1][n] = a1 + bias;
    tfb_s[2][n] = a2 + bias; tfb_s[3][n] = a3 + bias;
  }
  __syncthreads();
  {
    int n = t;
    const short* wk = Wqkv + (long)(256 + n) * 256;
    const short* wvp = Wqkv + (long)(512 + n) * 256;
    float k0=0,k1=0,k2=0,k3=0,v0=0,v1=0,v2=0,v3=0;
    for (int d = 0; d < 256; d += 8) {
      bfx8 wkv = *(const bfx8*)(wk + d);
      bfx8 wvv = *(const bfx8*)(wvp + d);
      #pragma unroll
      for (int j = 0; j < 8; ++j) {
        float f0 = tfb_s[0][d+j], f1 = tfb_s[1][d+j], f2 = tfb_s[2][d+j], f3 = tfb_s[3][d+j];
        float kw = bf2f(wkv[j]), vw = bf2f(wvv[j]);
        k0 += f0*kw; k1 += f1*kw; k2 += f2*kw; k3 += f3*kw;
        v0 += f0*vw; v1 += f1*vw; v2 += f2*vw; v3 += f3*vw;
      }
    }
    float bk = inb[256+n], bv = inb[512+n];
    khv[(b*4+0)*256+n]=k0+bk; khv[(b*4+1)*256+n]=k1+bk;
    khv[(b*4+2)*256+n]=k2+bk; khv[(b*4+3)*256+n]=k3+bk;
    vhv[(b*4+0)*256+n]=v0+bv; vhv[(b*4+1)*256+n]=v1+bv;
    vhv[(b*4+2)*256+n]=v2+bv; vhv[(b*4+3)*256+n]=v3+bv;
  }
}

// ---------------- local window attention (+ fused window mean -> oatm) ----------------
__global__ __launch_bounds__(256) void attn_local(const short* qk, const short* vhT,
                                                  short* oat, short* oatm) {
  __shared__ short Pl[4 * 64 * 72];
  const int lane = threadIdx.x & 63, h = threadIdx.x >> 6;
  const int lg = lane >> 4, li = lane & 15;
  const int bw = blockIdx.x;
  const int b = bw >> 6, wY = bw & 63;
  const long p0 = (long)bw * 64;

  bfx8 qf[4][2], kf[4][2];
  #pragma unroll
  for (int mi = 0; mi < 4; ++mi)
    #pragma unroll
    for (int ks = 0; ks < 2; ++ks) {
      qf[mi][ks] = *(const bfx8*)(qk + (p0 + 16 * mi + li) * 512 + h * 64 + 32 * ks + 8 * lg);
      kf[mi][ks] = *(const bfx8*)(qk + (p0 + 16 * mi + li) * 512 + 256 + h * 64 + 32 * ks + 8 * lg);
    }
  fx4 s[4][4] = {};
  #pragma unroll
  for (int mi = 0; mi < 4; ++mi)
    #pragma unroll
    for (int ni = 0; ni < 4; ++ni) {
      MFMA16(s[mi][ni], qf[mi][0], kf[ni][0]);
      MFMA16(s[mi][ni], qf[mi][1], kf[ni][1]);
    }
  #pragma unroll
  for (int mi = 0; mi < 4; ++mi)
    #pragma unroll
    for (int ni = 0; ni < 4; ++ni) s[mi][ni] *= 0.125f;

  #pragma unroll
  for (int mi = 0; mi < 4; ++mi)
    #pragma unroll
    for (int r = 0; r < 4; ++r) {
      float mx = fmaxf(fmaxf(s[mi][0][r], s[mi][1][r]), fmaxf(s[mi][2][r], s[mi][3][r]));
      for (int off = 1; off < 16; off <<= 1) mx = fmaxf(mx, __shfl_xor(mx, off));
      float e[4];
      float sum = 0.0f;
      #pragma unroll
      for (int ni = 0; ni < 4; ++ni) { e[ni] = expf(s[mi][ni][r] - mx); sum += e[ni]; }
      for (int off = 1; off < 16; off <<= 1) sum += __shfl_xor(sum, off);
      float inv = 1.0f / sum;
      int row = h * 64 + 16 * mi + 4 * lg + r;
      #pragma unroll
      for (int ni = 0; ni < 4; ++ni) Pl[row * 72 + 16 * ni + li] = f2bf(e[ni] * inv);
    }
  __syncthreads();

  fx4 o[4][4] = {};
  #pragma unroll
  for (int ks = 0; ks < 2; ++ks) {
    bfx8 pf[4], vf[4];
    #pragma unroll
    for (int mi = 0; mi < 4; ++mi)
      pf[mi] = *(const bfx8*)(&Pl[(h * 64 + 16 * mi + li) * 72 + 32 * ks + 8 * lg]);
    #pragma unroll
    for (int ni = 0; ni < 4; ++ni)
      vf[ni] = *(const bfx8*)(vhT + ((long)(b * 256 + h * 64 + 16 * ni + li)) * 4096 + wY * 64 + 32 * ks + 8 * lg);
    #pragma unroll
    for (int mi = 0; mi < 4; ++mi)
      #pragma unroll
      for (int ni = 0; ni < 4; ++ni) MFMA16(o[mi][ni], pf[mi], vf[ni]);
  }
  #pragma unroll
  for (int mi = 0; mi < 4; ++mi)
    #pragma unroll
    for (int ni = 0; ni < 4; ++ni)
      #pragma unroll
      for (int r = 0; r < 4; ++r)
        oat[(p0 + 16 * mi + 4 * lg + r) * 256 + h * 64 + 16 * ni + li] = f2bf(o[mi][ni][r]);

  #pragma unroll
  for (int ni = 0; ni < 4; ++ni) {
    float s2 = 0.0f;
    #pragma unroll
    for (int mi = 0; mi < 4; ++mi)
      #pragma unroll
      for (int r = 0; r < 4; ++r) s2 += o[mi][ni][r];
    s2 += __shfl_xor(s2, 16);
    s2 += __shfl_xor(s2, 32);
    if (lg == 0)
      oatm[(long)bw * 256 + h * 64 + 16 * ni + li] = f2bf(s2 * (1.0f / 64.0f));
  }
}

// ---------------- per-batch global chain (MFMA-batched over 64 windows): oatm -> gcon ----------------
#define GP 272

DEV void mm_stage(const short* srcA, const short* Bw, long ldb, const float* biasN,
                  short* dstL, float* dstG, int wv, int lg, int li) {
  fx4 acc[4][4] = {};
  const short* aRd = srcA + li * GP + lg * 8;
  const short* bR = Bw + (long)(wv * 64 + li) * ldb + lg * 8;
  for (int kc = 0; kc < 256; kc += 32) {
    bfx8 af[4], bf[4];
    #pragma unroll
    for (int mi = 0; mi < 4; ++mi) af[mi] = *(const bfx8*)(aRd + mi * 16 * GP + kc);
    #pragma unroll
    for (int ni = 0; ni < 4; ++ni) bf[ni] = *(const bfx8*)(bR + (long)ni * 16 * ldb + kc);
    #pragma unroll
    for (int mi = 0; mi < 4; ++mi)
      #pragma unroll
      for (int ni = 0; ni < 4; ++ni) MFMA16(acc[mi][ni], af[mi], bf[ni]);
  }
  #pragma unroll
  for (int mi = 0; mi < 4; ++mi)
    #pragma unroll
    for (int ni = 0; ni < 4; ++ni) {
      int col = wv * 64 + ni * 16 + li;
      float bn = biasN[col];
      #pragma unroll
      for (int r = 0; r < 4; ++r) {
        int row = mi * 16 + 4 * lg + r;
        float v = acc[mi][ni][r] + bn;
        if (dstL) dstL[row * GP + col] = f2bf(v);
        else dstG[(long)row * 256 + col] = v;
      }
    }
}

__global__ __launch_bounds__(256) void globk2(
    const short* oatm, const float* khv, const float* vhv,
    const short* Wo, const short* Wqkv, const short* Wep1,
    const float* ob, const float* inb, const float* ebc,
    float* gcon) {
  __shared__ short bufA[64 * GP];
  __shared__ short bufB[64 * GP];
  __shared__ float kh_s[4][256];
  __shared__ float vh_s[4][256];
  __shared__ float scb[16], pb[16];
  const int t = threadIdx.x;
  const int lane = t & 63, wv = t >> 6;
  const int lg = lane >> 4, li = lane & 15;
  const int b = blockIdx.x;

  { // stage oatm[b] -> bufA; load khv/vhv -> LDS
    #pragma unroll
    for (int i = 0; i < 8; ++i) {
      int chunk = i * 256 + t;
      int row = chunk >> 5, colc = (chunk & 31) * 8;
      *(bfx8*)(bufA + row * GP + colc) =
          *(const bfx8*)(oatm + ((long)(b * 64 + row)) * 256 + colc);
    }
    #pragma unroll
    for (int key = 0; key < 4; ++key) {
      kh_s[key][t] = khv[(long)(b * 4 + key) * 256 + t];
      vh_s[key][t] = vhv[(long)(b * 4 + key) * 256 + t];
    }
  }
  __syncthreads();
  // gq = bufA @ Wo^T + ob -> bufB
  mm_stage(bufA, Wo, 256, ob, bufB, nullptr, wv, lg, li);
  __syncthreads();
  // qhg = bufB @ Wq^T + inb -> bufA
  mm_stage(bufB, Wqkv, 256, inb, bufA, nullptr, wv, lg, li);
  __syncthreads();
  { // 4-key attention per (window p, head h)
    int p = t >> 2, h = t & 3;
    const short* qr = bufA + p * GP + h * 64;
    float sc[4];
    #pragma unroll
    for (int key = 0; key < 4; ++key) {
      float s = 0.0f;
      for (int d = 0; d < 64; d += 8) {
        bfx8 q8 = *(const bfx8*)(qr + d);
        #pragma unroll
        for (int j = 0; j < 8; ++j) s += bf2f(q8[j]) * kh_s[key][h * 64 + d + j];
      }
      sc[key] = s * 0.125f;
    }
    float mx = fmaxf(fmaxf(sc[0], sc[1]), fmaxf(sc[2], sc[3]));
    float e0 = expf(sc[0]-mx), e1 = expf(sc[1]-mx), e2 = expf(sc[2]-mx), e3 = expf(sc[3]-mx);
    float inv = 1.0f / (e0 + e1 + e2 + e3);
    e0 *= inv; e1 *= inv; e2 *= inv; e3 *= inv;
    short* orow = bufB + p * GP + h * 64;
    for (int d = 0; d < 64; ++d) {
      float o = e0*vh_s[0][h*64+d] + e1*vh_s[1][h*64+d] + e2*vh_s[2][h*64+d] + e3*vh_s[3][h*64+d];
      orow[d] = f2bf(o);
    }
  }
  __syncthreads();
  // glb = bufB @ Wo^T + ob -> bufA
  mm_stage(bufB, Wo, 256, ob, bufA, nullptr, wv, lg, li);
  __syncthreads();
  // gcon = bufA @ E1b^T + ebc -> global f32
  mm_stage(bufA, Wep1 + 256, 512, ebc, nullptr, gcon + (long)b * 64 * 256, wv, lg, li);
}

// ---------------- fused ep1 + ep2 + sigmoid: oat -> out ----------------
// One block per 128 rows. h-tile lives in LDS; ep2 accumulated via MFMA in two K-halves.
__global__ __launch_bounds__(256) void ep12(const short* oat, const short* Wcomb,
                                            const short* Wep2, const float* gcon,
                                            const float* e2b, float* out) {
  __shared__ short As[128 * 32];
  __shared__ short Bs[128 * 32];
  __shared__ short hl[128 * 140];
  const int lane = threadIdx.x & 63, wv = threadIdx.x >> 6;
  const int wm = wv >> 1, wn = wv & 1;
  const int lg = lane >> 4, li = lane & 15;
  const int m0 = (int)blockIdx.x * 128;
  const int srow = wv * 16 + (lane >> 2);
  const int scol = (lane & 3) * 8;
  const short* pA0 = oat + (long)(m0 + srow) * 256 + scol;
  const short* pA1 = oat + (long)(m0 + 64 + srow) * 256 + scol;
  short* ldsA = As + wv * 512;
  short* ldsB = Bs + wv * 512;
  const short* aRd = As + (wm * 64 + li) * 32 + lg * 8;
  const short* bRd = Bs + (wn * 64 + li) * 32 + lg * 8;

  fx4 eacc[2] = {};
  for (int half = 0; half < 2; ++half) {
    const short* B = Wcomb + (long)(half * 128) * 256;
    const short* pB0 = B + (long)srow * 256 + scol;
    const short* pB1 = B + (long)(64 + srow) * 256 + scol;
    fx4 acc[4][4] = {};
    for (int kc = 0; kc < 256; kc += 32) {
      gl_lds16(pA0 + kc, ldsA);
      gl_lds16(pA1 + kc, ldsA + 2048);
      gl_lds16(pB0 + kc, ldsB);
      gl_lds16(pB1 + kc, ldsB + 2048);
      __syncthreads();
      bfx8 af[4], bf[4];
      #pragma unroll
      for (int mi = 0; mi < 4; ++mi) af[mi] = *(const bfx8*)(aRd + mi * 16 * 32);
      #pragma unroll
      for (int ni = 0; ni < 4; ++ni) bf[ni] = *(const bfx8*)(bRd + ni * 16 * 32);
      #pragma unroll
      for (int mi = 0; mi < 4; ++mi)
        #pragma unroll
        for (int ni = 0; ni < 4; ++ni)
          MFMA16(acc[mi][ni], af[mi], bf[ni]);
      __syncthreads();
    }
    // epilogue: + gcon rowbias, gelu -> hl (bf16)
    #pragma unroll
    for (int mi = 0; mi < 4; ++mi)
      #pragma unroll
      for (int ni = 0; ni < 4; ++ni) {
        int coll = wn * 64 + ni * 16 + li;
        int colg = half * 128 + coll;
        #pragma unroll
        for (int r = 0; r < 4; ++r) {
          int rowl = wm * 64 + mi * 16 + 4 * lg + r;
          float v = acc[mi][ni][r] + gcon[(long)((m0 + rowl) >> 6) * 256 + colg];
          hl[rowl * 140 + coll] = f2bf(gelu_f(v));
        }
      }
    __syncthreads();
    // ep2 partial: K-half MFMA; wave wv owns rows wv*32..wv*32+31, all 16 e-cols
    #pragma unroll
    for (int kc = 0; kc < 128; kc += 32) {
      bfx8 bf2v = *(const bfx8*)(Wep2 + (long)li * 256 + half * 128 + kc + lg * 8);
      #pragma unroll
      for (int mi = 0; mi < 2; ++mi) {
        bfx8 af = *(const bfx8*)(hl + (wv * 32 + mi * 16 + li) * 140 + kc + lg * 8);
        MFMA16(eacc[mi], af, bf2v);
      }
    }
    __syncthreads();
  }
  #pragma unroll
  for (int mi = 0; mi < 2; ++mi)
    #pragma unroll
    for (int r = 0; r < 4; ++r) {
      int row = m0 + wv * 32 + mi * 16 + 4 * lg + r;
      out[(long)row * 16 + li] = 1.0f / (1.0f + expf(-(eacc[mi][r] + e2b[li])));
    }
}

// ---------------- host ----------------
extern "C" void kernel_launch(void* const* d_in, const int* in_sizes, int n_in,
                              void* d_out, int out_size, void* d_ws, size_t ws_size,
                              hipStream_t stream) {
  (void)in_sizes; (void)n_in; (void)out_size; (void)ws_size;
  const float* fm  = (const float*)d_in[0];
  const float* txt = (const float*)d_in[1];
  const float* w1  = (const float*)d_in[2];
  const float* b1  = (const float*)d_in[3];
  const float* w2  = (const float*)d_in[4];
  const float* b2  = (const float*)d_in[5];
  const float* gnw = (const float*)d_in[6];
  const float* gnb = (const float*)d_in[7];
  const float* inw = (const float*)d_in[8];
  const float* inb = (const float*)d_in[9];
  const float* ow  = (const float*)d_in[10];
  const float* ob  = (const float*)d_in[11];
  const float* tw  = (const float*)d_in[12];
  const float* tb  = (const float*)d_in[13];
  const float* e1w = (const float*)d_in[14];
  const float* e1b = (const float*)d_in[15];
  const float* e2w = (const float*)d_in[16];
  const float* e2b = (const float*)d_in[17];
  float* out = (float*)d_out;

  char* base = (char*)d_ws;
  size_t off = 0;
  auto alloc = [&](size_t bytes) -> char* {
    char* r = base + off;
    off = (off + bytes + 255) & ~(size_t)255;
    return r;
  };
  short* W1bf = (short*)alloc(256 * 256 * 2);
  short* W2t  = (short*)alloc((size_t)9 * 768 * 256 * 2);
  short* Wqkv = (short*)alloc(768 * 256 * 2);
  short* Wo   = (short*)alloc(256 * 256 * 2);
  short* Wcomb= (short*)alloc(256 * 256 * 2);
  float* ebc  = (float*)alloc(256 * 4);
  short* Wtxt = (short*)alloc(256 * 512 * 2);
  short* Wep1 = (short*)alloc(256 * 512 * 2);
  short* Wep2 = (short*)alloc(16 * 256 * 2);
  short* Tbf  = (short*)alloc((size_t)8 * 64 * 512 * 2);
  short* xP   = (short*)alloc((size_t)8 * 66 * 66 * 256 * 2);
  short* qkv  = (short*)alloc((size_t)8 * 4096 * 768 * 2);
  float* stats= (float*)alloc(64 * 4);
  short* Wf   = (short*)alloc((size_t)8 * 768 * 256 * 2);
  float* bfold= (float*)alloc((size_t)8 * 768 * 4);
  short* qk   = (short*)alloc((size_t)32768 * 512 * 2);
  short* vhT  = (short*)alloc((size_t)8 * 4096 * 256 * 2);
  short* oat  = (short*)alloc((size_t)8 * 4096 * 256 * 2);
  short* oatm = (short*)alloc(512 * 256 * 2);
  float* khv  = (float*)alloc(8 * 4 * 256 * 4);
  float* vhv  = (float*)alloc(8 * 4 * 256 * 4);
  float* gcon = (float*)alloc(512 * 256 * 4);

  hipMemsetAsync(stats, 0, 64 * 4, stream);

  CvtArgs ca;
  ca.s[0] = {w1,  W1bf, 256 * 256};
  ca.s[1] = {inw, Wqkv, 768 * 256};
  ca.s[2] = {ow,  Wo,   256 * 256};
  ca.s[3] = {tw,  Wtxt, 256 * 512};
  ca.s[4] = {e1w, Wep1, 256 * 512};
  ca.s[5] = {e2w, Wep2, 16 * 256};
  ca.s[6] = {txt, Tbf,  8 * 64 * 512};
  cvt_multi<<<dim3(128, 7), 256, 0, stream>>>(ca);
  cvt_conv2w<<<768, 256, 0, stream>>>(w2, W2t);
  ebc2<<<256, 64, 0, stream>>>(e1w, e1b, ob, ebc);
  globk_txt<<<8, 256, 0, stream>>>(Tbf, Wtxt, Wqkv, tb, inb, khv, vhv);
  wcombk<<<dim3(4, 4), 256, 0, stream>>>(ow, Wep1, Wcomb);

  tc1<<<512, 256, 0, stream>>>(fm, W1bf, b1, xP);

  conv2g<<<1536, 256, 0, stream>>>(xP, W2t, b2, qkv, stats);

  gn_fold<<<1536, 256, 0, stream>>>(stats, gnw, gnb, inw, inb, Wf, bfold);

  { // packed qk + v projections
    GemmP gq{};
    gq.A = qkv; gq.lda = 768; gq.sA = 4096L * 768;
    gq.B = Wf; gq.ldb = 256; gq.sB = 768L * 256;
    gq.O = qk; gq.ldo = 512; gq.sO = 4096L * 512;
    gq.biasN = bfold; gq.sBN = 768;
    gq.aShift = 256;
    gq.M = 4096; gq.N = 512; gq.K = 256;
    GemmP gv{};
    gv.A = Wf + 512 * 256; gv.lda = 256; gv.sA = 768L * 256;
    gv.B = qkv + 512; gv.ldb = 768; gv.sB = 4096L * 768;
    gv.O = vhT; gv.ldo = 4096; gv.sO = 256L * 4096;
    gv.biasM = bfold + 512; gv.sBM = 768;
    gv.M = 256; gv.N = 4096; gv.K = 256;
    projk<<<1536, 256, 0, stream>>>(gq, gv);
  }

  attn_local<<<512, 256, 0, stream>>>(qk, vhT, oat, oatm);

  globk2<<<8, 256, 0, stream>>>(oatm, khv, vhv, Wo, Wqkv, Wep1, ob, inb, ebc, gcon);

  ep12<<<256, 256, 0, stream>>>(oat, Wcomb, Wep2, gcon, e2b, out);
}